// Round 13
// baseline (1095.427 us; speedup 1.0000x reference)
//
#include <hip/hip_runtime.h>
#include <hip/hip_bf16.h>
#include <stdint.h>

// Problem constants
constexpr int Bn = 8;              // batches
constexpr int Np = 8192;           // points per batch
constexpr int Gc = 512;            // FPS centers / groups
constexpr int Kn = 32;             // knn neighbors
constexpr int Mrows = Bn * Gc * Kn;  // 131072 encoder rows
constexpr float LNEPS = 1e-5f;

using f32x2  = __attribute__((ext_vector_type(2))) float;
using f32x4  = __attribute__((ext_vector_type(4))) float;
using bf16x8 = __attribute__((ext_vector_type(8))) __bf16;

#define DEVINL __device__ __forceinline__

// ---- DPP wave64 reductions (canonical GCN sequence; validated R4-R12) ------
DEVINL unsigned wave_red_max_u32(unsigned x) {
    int v = (int)x, t;
    t = __builtin_amdgcn_update_dpp(0, v, 0x111, 0xf, 0xf, false); v = ((unsigned)v > (unsigned)t) ? v : t;
    t = __builtin_amdgcn_update_dpp(0, v, 0x112, 0xf, 0xf, false); v = ((unsigned)v > (unsigned)t) ? v : t;
    t = __builtin_amdgcn_update_dpp(0, v, 0x114, 0xf, 0xf, false); v = ((unsigned)v > (unsigned)t) ? v : t;
    t = __builtin_amdgcn_update_dpp(0, v, 0x118, 0xf, 0xf, false); v = ((unsigned)v > (unsigned)t) ? v : t;
    t = __builtin_amdgcn_update_dpp(0, v, 0x142, 0xa, 0xf, false); v = ((unsigned)v > (unsigned)t) ? v : t;
    t = __builtin_amdgcn_update_dpp(0, v, 0x143, 0xc, 0xf, false); v = ((unsigned)v > (unsigned)t) ? v : t;
    return (unsigned)__builtin_amdgcn_readlane(v, 63);
}
DEVINL unsigned wave_red_min_u32(unsigned x) {
    int v = (int)x, t;
    t = __builtin_amdgcn_update_dpp(-1, v, 0x111, 0xf, 0xf, false); v = ((unsigned)v < (unsigned)t) ? v : t;
    t = __builtin_amdgcn_update_dpp(-1, v, 0x112, 0xf, 0xf, false); v = ((unsigned)v < (unsigned)t) ? v : t;
    t = __builtin_amdgcn_update_dpp(-1, v, 0x114, 0xf, 0xf, false); v = ((unsigned)v < (unsigned)t) ? v : t;
    t = __builtin_amdgcn_update_dpp(-1, v, 0x118, 0xf, 0xf, false); v = ((unsigned)v < (unsigned)t) ? v : t;
    t = __builtin_amdgcn_update_dpp(-1, v, 0x142, 0xa, 0xf, false); v = ((unsigned)v < (unsigned)t) ? v : t;
    t = __builtin_amdgcn_update_dpp(-1, v, 0x143, 0xc, 0xf, false); v = ((unsigned)v < (unsigned)t) ? v : t;
    return (unsigned)__builtin_amdgcn_readlane(v, 63);
}
// u64 min-reduce (keys monotone, all distinct) -- validated in KNN v3 (R10)
DEVINL unsigned long long wave_red_min_u64(unsigned long long x) {
    unsigned lo = (unsigned)x, hi = (unsigned)(x >> 32);
#define RSTEP(ctl, rm) { \
    unsigned tlo = (unsigned)__builtin_amdgcn_update_dpp(-1, (int)lo, ctl, rm, 0xf, false); \
    unsigned thi = (unsigned)__builtin_amdgcn_update_dpp(-1, (int)hi, ctl, rm, 0xf, false); \
    unsigned long long o = ((unsigned long long)thi << 32) | tlo; \
    unsigned long long c = ((unsigned long long)hi << 32) | lo; \
    if (o < c) { lo = tlo; hi = thi; } }
    RSTEP(0x111, 0xf) RSTEP(0x112, 0xf) RSTEP(0x114, 0xf) RSTEP(0x118, 0xf)
    RSTEP(0x142, 0xa) RSTEP(0x143, 0xc)
#undef RSTEP
    unsigned flo = (unsigned)__builtin_amdgcn_readlane((int)lo, 63);
    unsigned fhi = (unsigned)__builtin_amdgcn_readlane((int)hi, 63);
    return ((unsigned long long)fhi << 32) | flo;
}
// Order-preserving float -> u32 key (handles negative floats; radix-sort trick)
DEVINL unsigned fkey(float f) {
    unsigned b = __float_as_uint(f);
    return b ^ (unsigned)(((int)b >> 31) | (int)0x80000000);
}

// ---------------------------------------------------------------------------
// Fused FPS + KNN + h1 persistent kernel. Grid = 256 blocks x 512 threads,
// 131.1KB LDS/block => exactly 1 block/CU => all 256 blocks co-resident
// (no deadlock possible in the producer-consumer handshake).
//
// Blocks 0..7   (producers): R8-exact FPS (390us validated: 8 waves, DPP
//   value-max -> equality scan -> DPP idx-min -> lane0 atomicMax(LDS, 3-slot
//   rotation) -> barrier -> b64 read). Publishes winner INDEX cidx[b][g]
//   (relaxed agent atomic) + release-increments cnt[b]. No centers buffer:
//   consumers read xyz[wi] directly (immutable input => no coherence hazard).
//
// Blocks 8..255 (consumers, 31/batch): iterate group-pairs p = cj, cj+31,...
//   acquire-spin (t0 + s_sleep) until cnt[b] >= 2p+2, then run KNN v3 body
//   (validated R10) verbatim -- waves 0-3 -> group 2p, waves 4-7 -> 2p+1,
//   separate wl regions -- then 128-candidate rank merge -> feats into LDS ->
//   h1 math (validated R1) verbatim, h1b written directly (feats buffer and
//   the separate knn/h1 kernels eliminated; knn+h1 hide under fps).
// ---------------------------------------------------------------------------
__global__ __launch_bounds__(512) void fps_knn_h1_kernel(
    const float* __restrict__ xyz, const float* __restrict__ color,
    const float* __restrict__ w1, const float* __restrict__ b1,
    const float* __restrict__ g1, const float* __restrict__ be1,
    __hip_bfloat16* __restrict__ h1b,
    unsigned* __restrict__ cnt, unsigned* __restrict__ cidx)
{
    alignas(16) __shared__ char shraw[131104];
    const int t = threadIdx.x;

    if (blockIdx.x < 8) {
        // ============== PRODUCER: FPS (R8-exact) ==============
        const int b = blockIdx.x;
        f32x4* pts = (f32x4*)shraw;
        unsigned long long* sred = (unsigned long long*)(shraw + 131072);
        const float* P = xyz + (size_t)b * Np * 3;
        f32x2 X[8], Y[8], Z[8], MD[8];
#pragma unroll
        for (int i = 0; i < 8; ++i) {
            int p0 = (2 * i) * 512 + t;
            int p1 = p0 + 512;
            float x0 = P[p0 * 3 + 0], y0 = P[p0 * 3 + 1], z0 = P[p0 * 3 + 2];
            float x1 = P[p1 * 3 + 0], y1 = P[p1 * 3 + 1], z1 = P[p1 * 3 + 2];
            X[i] = f32x2{x0, x1}; Y[i] = f32x2{y0, y1}; Z[i] = f32x2{z0, z1};
            pts[p0] = f32x4{x0, y0, z0, 0.f};
            pts[p1] = f32x4{x1, y1, z1, 0.f};
            MD[i] = f32x2{__builtin_inff(), __builtin_inff()};
        }
        if (t < 3) sred[t] = 0ull;
        if (t == 0) {
            __hip_atomic_store(&cidx[b * Gc + 0], 0u, __ATOMIC_RELAXED, __HIP_MEMORY_SCOPE_AGENT);
            __hip_atomic_fetch_add(&cnt[b], 1u, __ATOMIC_RELEASE, __HIP_MEMORY_SCOPE_AGENT);
        }
        __syncthreads();
        int last = 0;
        for (int g = 1; g < Gc; ++g) {
            const f32x4 c4 = pts[last];
            const f32x2 cx = {c4.x, c4.x}, cy = {c4.y, c4.y}, cz = {c4.z, c4.z};
            f32x2 bv2 = {0.f, 0.f};
#pragma unroll
            for (int i = 0; i < 8; ++i) {
                f32x2 dx = X[i] - cx;
                f32x2 dy = Y[i] - cy;
                f32x2 dz = Z[i] - cz;
                f32x2 d  = (dx * dx + dy * dy) + dz * dz;   // exact ref form (validated)
                f32x2 m  = MD[i];
                m.x = fminf(m.x, d.x); m.y = fminf(m.y, d.y);
                MD[i] = m;
                bv2.x = fmaxf(bv2.x, m.x); bv2.y = fmaxf(bv2.y, m.y);
            }
            const float bv = fmaxf(bv2.x, bv2.y);
            const unsigned wmax = wave_red_max_u32(__float_as_uint(bv));
            unsigned idx = 0xffffffffu;
#pragma unroll
            for (int i = 7; i >= 0; --i) {
                if (__float_as_uint(MD[i].y) == wmax) idx = (unsigned)((2 * i + 1) * 512 + t);
                if (__float_as_uint(MD[i].x) == wmax) idx = (unsigned)((2 * i) * 512 + t);
            }
            const unsigned widx = wave_red_min_u32(idx);
            if ((t & 63) == 0) {
                unsigned long long pack =
                    ((unsigned long long)wmax << 32) | (unsigned long long)(~widx);
                atomicMax(&sred[g % 3], pack);
            }
            if (t == 1) sred[(g + 1) % 3] = 0ull;
            __syncthreads();
            const unsigned long long w = sred[g % 3];
            const int wi = (int)(~(unsigned)w);
            if (t == 0) {
                __hip_atomic_store(&cidx[b * Gc + g], (unsigned)wi, __ATOMIC_RELAXED, __HIP_MEMORY_SCOPE_AGENT);
                __hip_atomic_fetch_add(&cnt[b], 1u, __ATOMIC_RELEASE, __HIP_MEMORY_SCOPE_AGENT);
            }
            last = wi;
        }
        return;
    }

    // ============== CONSUMER: KNN v3 + h1 ==============
    const int cid  = blockIdx.x - 8;     // 0..247
    const int cb   = cid & 7;            // batch
    const int cj   = cid >> 3;           // 0..30
    const int wave = t >> 6;             // 0..7
    const int sub  = wave & 3;           // wave within 4-wave group
    const int gsel = wave >> 2;          // 0 or 1: which group of the pair
    const int lane = t & 63;
    unsigned long long* wl = (unsigned long long*)shraw;       // [2][128]
    float* fs = (float*)(shraw + 2048);                        // [2][32][6]
    const float* P = xyz + (size_t)cb * Np * 3;
    const float* C = color + (size_t)cb * Np * 3;
    const int pbase = sub * 2048 + lane;

    for (int p = cj; p < 256; p += 31) {
        const int g = 2 * p + gsel;
        if (t == 0) {
            while ((int)__hip_atomic_load(&cnt[cb], __ATOMIC_ACQUIRE, __HIP_MEMORY_SCOPE_AGENT) < 2 * p + 2)
                __builtin_amdgcn_s_sleep(8);
        }
        __syncthreads();
        const unsigned wic = __hip_atomic_load(&cidx[cb * Gc + g], __ATOMIC_RELAXED, __HIP_MEMORY_SCOPE_AGENT);
        const float cx = P[wic * 3 + 0], cy = P[wic * 3 + 1], cz = P[wic * 3 + 2];
        const float cc = __fadd_rn(__fadd_rn(__fmul_rn(cx, cx), __fmul_rn(cy, cy)), __fmul_rn(cz, cz));
        float dr[32];
#pragma unroll
        for (int i = 0; i < 32; ++i) {
            int pp = pbase + i * 64;
            float px = P[pp * 3 + 0], py = P[pp * 3 + 1], pz = P[pp * 3 + 2];
            float dot = __fadd_rn(__fadd_rn(__fmul_rn(cx, px), __fmul_rn(cy, py)), __fmul_rn(cz, pz));
            float q   = __fadd_rn(__fadd_rn(__fmul_rn(px, px), __fmul_rn(py, py)), __fmul_rn(pz, pz));
            dr[i] = __fadd_rn(__fadd_rn(__fmul_rn(-2.0f, dot), cc), q);
        }
        unsigned excl = 0;
        for (int k = 0; k < Kn; ++k) {
            float bd = __builtin_inff();
            int   bs = 0;
#pragma unroll
            for (int i = 0; i < 32; ++i) {
                float d = ((excl >> i) & 1u) ? __builtin_inff() : dr[i];
                if (d < bd) { bd = d; bs = i; }
            }
            unsigned gidx = (unsigned)(pbase + bs * 64);
            unsigned long long win = wave_red_min_u64(
                ((unsigned long long)fkey(bd) << 32) | (unsigned long long)gidx);
            if (lane == 0) wl[gsel * 128 + sub * 32 + k] = win;
            unsigned widx = (unsigned)win;
            if ((widx & 63) == (unsigned)lane) excl |= 1u << ((widx >> 6) & 31);
        }
        __syncthreads();
        // rank merge: threads 0..127 -> group gsel=0, threads 256..383 -> gsel=1
        {
            const int tt = t & 255, half = t >> 8;
            if (tt < 128) {
                const unsigned long long my = wl[half * 128 + tt];
                int rank = 0;
                for (int j = 0; j < 128; ++j) rank += (wl[half * 128 + j] < my) ? 1 : 0;
                if (rank < Kn) {
                    unsigned gi = (unsigned)my;
                    float px = P[gi * 3 + 0], py = P[gi * 3 + 1], pz = P[gi * 3 + 2];
                    float* F = fs + (half * 32 + rank) * 6;
                    F[0] = px - cx; F[1] = py - cy; F[2] = pz - cz;   // this thread's wave
                    F[3] = C[gi * 3 + 0]; F[4] = C[gi * 3 + 1]; F[5] = C[gi * 3 + 2];
                }
            }
        }
        __syncthreads();
        // h1 for the 64 rows of this pair (validated h1 math, feats from LDS)
#pragma unroll
        for (int rr = 0; rr < 8; ++rr) {
            const int r  = wave * 8 + rr;        // 0..63
            const int gg = r >> 5, k = r & 31;
            const float* F = fs + (gg * 32 + k) * 6;
            float fr[6];
#pragma unroll
            for (int i = 0; i < 6; ++i) fr[i] = F[i];
            const int c0 = lane * 2;
            float a0 = b1[c0], a1 = b1[c0 + 1];
#pragma unroll
            for (int i = 0; i < 6; ++i) {
                a0 = fmaf(w1[c0 * 6 + i], fr[i], a0);
                a1 = fmaf(w1[(c0 + 1) * 6 + i], fr[i], a1);
            }
            float s = a0 + a1;
#pragma unroll
            for (int m = 1; m < 64; m <<= 1) s += __shfl_xor(s, m, 64);
            float mu = s * (1.f / 128.f);
            float d0 = a0 - mu, d1 = a1 - mu;
            float q = d0 * d0 + d1 * d1;
#pragma unroll
            for (int m = 1; m < 64; m <<= 1) q += __shfl_xor(q, m, 64);
            float iv = rsqrtf(q * (1.f / 128.f) + LNEPS);
            float y0 = fmaxf(0.f, d0 * iv * g1[c0] + be1[c0]);
            float y1 = fmaxf(0.f, d1 * iv * g1[c0 + 1] + be1[c0 + 1]);
            __hip_bfloat16* dst = h1b + ((size_t)(cb * Gc + 2 * p + gg) * 32 + k) * 128 + c0;
            dst[0] = __float2bfloat16(y0);
            dst[1] = __float2bfloat16(y1);
        }
        __syncthreads();
    }
}

// ---------------------------------------------------------------------------
// Weight cast f32 -> bf16 (w2, w3, w4)
// ---------------------------------------------------------------------------
__global__ void cast_w_kernel(const float* __restrict__ w2, const float* __restrict__ w3,
                              const float* __restrict__ w4,
                              __hip_bfloat16* __restrict__ o2, __hip_bfloat16* __restrict__ o3,
                              __hip_bfloat16* __restrict__ o4)
{
    int i = blockIdx.x * 256 + threadIdx.x;   // grid covers 262144
    if (i < 256 * 128) o2[i] = __float2bfloat16(w2[i]);
    o3[i] = __float2bfloat16(w3[i]);
    o4[i] = __float2bfloat16(w4[i]);
}

// ---------------------------------------------------------------------------
// GEMM: C[m,n] = sum_k A[m,k] * W[n,k]  (+ epilogues). BM=128, 8 waves.
// EPI 3: +bias, bf16 high-half store + fused per-group col-max into cols 0..255
// EPI 2: +bias, max over 32-row groups, f32 out
// EPI 4: +bias, f32 full-row store to outF (P1 = group-part of h3)
// EPI 6: +P1[grp] (from outF, f32), LayerNorm(BN)*gamma+beta, ReLU, bf16
// ---------------------------------------------------------------------------
template <int BN, int BK, int EPI>
__global__ __launch_bounds__(512, 2) void gemm_kernel(
    const __hip_bfloat16* A, int lda,
    const __hip_bfloat16* __restrict__ Bw, int ldb, int nkt,
    const float* __restrict__ bias,
    const float* __restrict__ gamma, const float* __restrict__ beta,
    __hip_bfloat16* outB, int ocol0,
    float* __restrict__ outF)
{
    constexpr int BM = 128;
    constexpr int WN = BN / 4;
    constexpr int NI = WN / 16;
    constexpr int MI = 4;
    constexpr int RB = BK * 2;           // row bytes in LDS
    constexpr int SWM = BK / 8 - 1;      // swizzle mask (chunks per row - 1)
    constexpr int A_ELE = BM * BK;
    constexpr int B_ELE = BN * BK;
    constexpr int BUF = A_ELE + B_ELE;
    constexpr int ACH = A_ELE * 2 / 16 / 512;
    constexpr int BCH = B_ELE * 2 / 16 / 512;
    __shared__ __hip_bfloat16 smem[2 * BUF];

    const int tid  = threadIdx.x;
    const int wid  = tid >> 6, lane = tid & 63;
    const int wm   = wid >> 2, wn = wid & 3;
    const int lrow = lane & 15, lq = lane >> 4;
    const int m0   = blockIdx.x * BM;

    f32x4 acc[MI][NI] = {};

    auto stage = [&](int buf, int k0) {
        const char* Ab = (const char*)A + ((size_t)m0 * lda + k0) * 2;
        const char* Bb = (const char*)Bw + (size_t)k0 * 2;
        char* sA = (char*)(smem + (size_t)buf * BUF);
        char* sB = sA + A_ELE * 2;
#pragma unroll
        for (int i = 0; i < ACH; ++i) {
            int chunk = i * 512 + tid;
            int Pp = chunk * 16;
            int row = Pp / RB;
            int kb = (Pp % RB) ^ ((row & SWM) << 4);
            const void* g = Ab + (size_t)row * (lda * 2) + kb;
            void* l = sA + (i * 512 + wid * 64) * 16;
            __builtin_amdgcn_global_load_lds((const __attribute__((address_space(1))) void*)g,
                                             (__attribute__((address_space(3))) void*)l, 16, 0, 0);
        }
#pragma unroll
        for (int i = 0; i < BCH; ++i) {
            int chunk = i * 512 + tid;
            int Pp = chunk * 16;
            int n = Pp / RB;
            int kb = (Pp % RB) ^ ((n & SWM) << 4);
            const void* g = Bb + (size_t)n * (ldb * 2) + kb;
            void* l = sB + (i * 512 + wid * 64) * 16;
            __builtin_amdgcn_global_load_lds((const __attribute__((address_space(1))) void*)g,
                                             (__attribute__((address_space(3))) void*)l, 16, 0, 0);
        }
    };

    auto compute = [&](int buf) {
        const char* sA = (const char*)(smem + (size_t)buf * BUF);
        const char* sB = sA + A_ELE * 2;
#pragma unroll
        for (int kk = 0; kk < BK / 32; ++kk) {
            bf16x8 af[MI], bfv[NI];
#pragma unroll
            for (int mi = 0; mi < MI; ++mi) {
                int row = wm * 64 + mi * 16 + lrow;
                int off = row * RB + ((kk * 64 + lq * 16) ^ ((row & SWM) << 4));
                af[mi] = *(const bf16x8*)(sA + off);
            }
#pragma unroll
            for (int ni = 0; ni < NI; ++ni) {
                int n = wn * WN + ni * 16 + lrow;
                int off = n * RB + ((kk * 64 + lq * 16) ^ ((n & SWM) << 4));
                bfv[ni] = *(const bf16x8*)(sB + off);
            }
#pragma unroll
            for (int mi = 0; mi < MI; ++mi)
#pragma unroll
                for (int ni = 0; ni < NI; ++ni)
                    acc[mi][ni] = __builtin_amdgcn_mfma_f32_16x16x32_bf16(af[mi], bfv[ni], acc[mi][ni], 0, 0, 0);
        }
    };

    stage(0, 0);
    __syncthreads();
    int cur = 0;
    for (int kt = 0; kt < nkt; ++kt) {
        if (kt + 1 < nkt) stage(cur ^ 1, (kt + 1) * BK);
        compute(cur);
        __syncthreads();
        cur ^= 1;
    }

    float bv[NI] = {};
    if constexpr (EPI != 6) {
#pragma unroll
        for (int ni = 0; ni < NI; ++ni) bv[ni] = bias[wn * WN + ni * 16 + lrow];
    }

    if constexpr (EPI == 3) {
        // high-half store (h2 result, cols 256..511)
#pragma unroll
        for (int mi = 0; mi < MI; ++mi)
#pragma unroll
            for (int ni = 0; ni < NI; ++ni) {
                int col = ocol0 + wn * WN + ni * 16 + lrow;
#pragma unroll
                for (int j = 0; j < 4; ++j) {
                    int row = wm * 64 + mi * 16 + lq * 4 + j;
                    outB[(size_t)(m0 + row) * 512 + col] = __float2bfloat16(acc[mi][ni][j] + bv[ni]);
                }
            }
        // fused hgmax: per-group (32-row) col-max, broadcast into cols 0..255
        float* hgp = (float*)smem;   // [4][256] f32; safe after loop's last barrier
#pragma unroll
        for (int mi2 = 0; mi2 < 2; ++mi2) {
#pragma unroll
            for (int ni = 0; ni < NI; ++ni) {
                float m = -__builtin_inff();
#pragma unroll
                for (int mh = 0; mh < 2; ++mh) {
                    int mi = mi2 * 2 + mh;
#pragma unroll
                    for (int j = 0; j < 4; ++j) m = fmaxf(m, acc[mi][ni][j] + bv[ni]);
                }
                m = fmaxf(m, __shfl_xor(m, 16, 64));
                m = fmaxf(m, __shfl_xor(m, 32, 64));
                if (lq == 0)
                    hgp[(wm * 2 + mi2) * 256 + wn * WN + ni * 16 + lrow] = m;
            }
        }
        __syncthreads();
#pragma unroll 4
        for (int i = 0; i < 64; ++i) {
            int idx = i * 512 + tid;            // 128 rows x 256 cols
            int row = idx >> 8, col = idx & 255;
            outB[(size_t)(m0 + row) * 512 + col] = __float2bfloat16(hgp[(row >> 5) * 256 + col]);
        }
    } else if constexpr (EPI == 4) {
#pragma unroll
        for (int mi = 0; mi < MI; ++mi)
#pragma unroll
            for (int ni = 0; ni < NI; ++ni) {
                int col = wn * WN + ni * 16 + lrow;
#pragma unroll
                for (int j = 0; j < 4; ++j) {
                    int row = wm * 64 + mi * 16 + lq * 4 + j;
                    outF[(size_t)(m0 + row) * 512 + col] = acc[mi][ni][j] + bv[ni];
                }
            }
    } else if constexpr (EPI == 6) {
        float gv[NI], bev[NI];
#pragma unroll
        for (int ni = 0; ni < NI; ++ni) {
            int col = wn * WN + ni * 16 + lrow;
            gv[ni] = gamma[col]; bev[ni] = beta[col];
        }
        {
            // add group-part P1 (f32, includes b3), uniform across the 32-row group
            const float* P1 = outF;
#pragma unroll
            for (int mi = 0; mi < MI; ++mi) {
                int grow = (m0 >> 5) + wm * 2 + (mi >> 1);
#pragma unroll
                for (int ni = 0; ni < NI; ++ni) {
                    float ad = P1[(size_t)grow * 512 + (wn * WN + ni * 16 + lrow)];
#pragma unroll
                    for (int j = 0; j < 4; ++j) acc[mi][ni][j] += ad;
                }
            }
        }

        float* rs  = (float*)smem;
        float* rq  = rs + BM * 4;
        float* rmu = rq + BM * 4;
        float* riv = rmu + BM;
#pragma unroll
        for (int mi = 0; mi < MI; ++mi) {
#pragma unroll
            for (int j = 0; j < 4; ++j) {
                float s = 0.f, q = 0.f;
#pragma unroll
                for (int ni = 0; ni < NI; ++ni) { float v = acc[mi][ni][j]; s += v; q += v * v; }
#pragma unroll
                for (int m = 1; m < 16; m <<= 1) { s += __shfl_xor(s, m, 64); q += __shfl_xor(q, m, 64); }
                if (lrow == 0) {
                    int row = wm * 64 + mi * 16 + lq * 4 + j;
                    rs[row * 4 + wn] = s;
                    rq[row * 4 + wn] = q;
                }
            }
        }
        __syncthreads();
        if (tid < BM) {
            float S = rs[tid * 4 + 0] + rs[tid * 4 + 1] + rs[tid * 4 + 2] + rs[tid * 4 + 3];
            float Q = rq[tid * 4 + 0] + rq[tid * 4 + 1] + rq[tid * 4 + 2] + rq[tid * 4 + 3];
            float mu = S * (1.f / BN);
            float var = Q * (1.f / BN) - mu * mu;
            rmu[tid] = mu;
            riv[tid] = rsqrtf(var + LNEPS);
        }
        __syncthreads();
#pragma unroll
        for (int mi = 0; mi < MI; ++mi)
#pragma unroll
            for (int j = 0; j < 4; ++j) {
                int row = wm * 64 + mi * 16 + lq * 4 + j;
                float mu = rmu[row], iv = riv[row];
#pragma unroll
                for (int ni = 0; ni < NI; ++ni) {
                    float v = (acc[mi][ni][j] - mu) * iv * gv[ni] + bev[ni];
                    v = fmaxf(v, 0.f);
                    outB[(size_t)(m0 + row) * 512 + (wn * WN + ni * 16 + lrow)] = __float2bfloat16(v);
                }
            }
    } else {
#pragma unroll
        for (int grp = 0; grp < 2; ++grp) {
            float mx[NI];
#pragma unroll
            for (int ni = 0; ni < NI; ++ni) {
                float m = -__builtin_inff();
#pragma unroll
                for (int mh = 0; mh < 2; ++mh) {
                    int mi = grp * 2 + mh;
#pragma unroll
                    for (int j = 0; j < 4; ++j) m = fmaxf(m, acc[mi][ni][j] + bv[ni]);
                }
                mx[ni] = m;
            }
#pragma unroll
            for (int ni = 0; ni < NI; ++ni) {
                mx[ni] = fmaxf(mx[ni], __shfl_xor(mx[ni], 16, 64));
                mx[ni] = fmaxf(mx[ni], __shfl_xor(mx[ni], 32, 64));
            }
            if (lq == 0) {
                int grow = (m0 >> 5) + wm * 2 + grp;
#pragma unroll
                for (int ni = 0; ni < NI; ++ni)
                    outF[(size_t)grow * 512 + wn * WN + ni * 16 + lrow] = mx[ni];
            }
        }
    }
}

// ---------------------------------------------------------------------------
extern "C" void kernel_launch(void* const* d_in, const int* in_sizes, int n_in,
                              void* d_out, int out_size, void* d_ws, size_t ws_size,
                              hipStream_t stream)
{
    const float* xyz   = (const float*)d_in[0];
    const float* color = (const float*)d_in[1];
    const float* w1  = (const float*)d_in[2];
    const float* b1  = (const float*)d_in[3];
    const float* g1  = (const float*)d_in[4];
    const float* be1 = (const float*)d_in[5];
    const float* w2  = (const float*)d_in[6];
    const float* b2  = (const float*)d_in[7];
    const float* w3  = (const float*)d_in[8];
    const float* b3  = (const float*)d_in[9];
    const float* g2  = (const float*)d_in[10];
    const float* be2 = (const float*)d_in[11];
    const float* w4  = (const float*)d_in[12];
    const float* b4  = (const float*)d_in[13];
    float* out = (float*)d_out;

    char* ws = (char*)d_ws;
    size_t off = 0;
    auto alloc = [&](size_t bytes) -> void* {
        void* p = ws + off;
        off += (bytes + 255) & ~(size_t)255;
        return p;
    };
    unsigned* cnt       = (unsigned*)alloc(8 * 4);
    unsigned* cidx      = (unsigned*)alloc((size_t)Bn * Gc * 4);
    __hip_bfloat16* w2b = (__hip_bfloat16*)alloc((size_t)256 * 128 * 2);
    __hip_bfloat16* w3b = (__hip_bfloat16*)alloc((size_t)512 * 512 * 2);
    __hip_bfloat16* w4b = (__hip_bfloat16*)alloc((size_t)512 * 512 * 2);
    __hip_bfloat16* h1b = (__hip_bfloat16*)alloc((size_t)Mrows * 128 * 2);
    __hip_bfloat16* x3  = (__hip_bfloat16*)alloc((size_t)Mrows * 512 * 2);
    // P1 [4096][512] f32 (8.4MB) aliases h1b (33.5MB, dead after the h2 gemm)
    float* P1 = (float*)h1b;
    (void)ws_size; (void)in_sizes; (void)n_in; (void)out_size;

    // zero the producer progress counters (ws is poisoned once, never re-poisoned)
    hipMemsetAsync(cnt, 0, 8 * 4, stream);
    // fused fps(8 producer blocks) + knn/h1(248 consumer blocks); 131.1KB LDS
    // => 1 block/CU => all 256 blocks co-resident => handshake deadlock-free
    fps_knn_h1_kernel<<<256, 512, 0, stream>>>(xyz, color, w1, b1, g1, be1, h1b, cnt, cidx);
    cast_w_kernel<<<1024, 256, 0, stream>>>(w2, w3, w4, w2b, w3b, w4b);
    // h2: A=h1b (K=128), writes h2 into x3 cols 256..511 + hg broadcast into 0..255
    gemm_kernel<256, 32, 3><<<Mrows / 128, 512, 0, stream>>>(h1b, 128, w2b, 128, 4,  b2, nullptr, nullptr, x3, 256, nullptr);
    // P1[g][o] = hg[g] @ w3[:, :256]^T + b3   (one x3 row per group via lda=512*32)
    gemm_kernel<512, 32, 4><<<Bn * Gc / 128, 512, 0, stream>>>(x3, 512 * 32, w3b, 512, 8, b3, nullptr, nullptr, nullptr, 0, P1);
    // h3: K=256 row-part (A = x3 cols 256.., W = w3 cols 256..), + P1[grp], LN, ReLU, in-place
    gemm_kernel<512, 32, 6><<<Mrows / 128, 512, 0, stream>>>(x3 + 256, 512, w3b + 256, 512, 8, nullptr, g2, be2, x3, 0, P1);
    // h4: K=512, group max-pool, f32 out
    gemm_kernel<512, 32, 2><<<Mrows / 128, 512, 0, stream>>>(x3, 512, w4b, 512, 16, b4, nullptr, nullptr, nullptr, 0, out);
}

// Round 14
// 649.111 us; speedup vs baseline: 1.6876x; 1.6876x over previous
//
#include <hip/hip_runtime.h>
#include <hip/hip_bf16.h>
#include <stdint.h>

// Problem constants
constexpr int Bn = 8;              // batches
constexpr int Np = 8192;           // points per batch
constexpr int Gc = 512;            // FPS centers / groups
constexpr int Kn = 32;             // knn neighbors
constexpr int Mrows = Bn * Gc * Kn;  // 131072 encoder rows
constexpr float LNEPS = 1e-5f;

using f32x2  = __attribute__((ext_vector_type(2))) float;
using f32x4  = __attribute__((ext_vector_type(4))) float;
using bf16x8 = __attribute__((ext_vector_type(8))) __bf16;

#define DEVINL __device__ __forceinline__

// ---- DPP wave64 reductions (canonical GCN sequence; validated R4-R13) ------
DEVINL unsigned wave_red_max_u32(unsigned x) {
    int v = (int)x, t;
    t = __builtin_amdgcn_update_dpp(0, v, 0x111, 0xf, 0xf, false); v = ((unsigned)v > (unsigned)t) ? v : t;
    t = __builtin_amdgcn_update_dpp(0, v, 0x112, 0xf, 0xf, false); v = ((unsigned)v > (unsigned)t) ? v : t;
    t = __builtin_amdgcn_update_dpp(0, v, 0x114, 0xf, 0xf, false); v = ((unsigned)v > (unsigned)t) ? v : t;
    t = __builtin_amdgcn_update_dpp(0, v, 0x118, 0xf, 0xf, false); v = ((unsigned)v > (unsigned)t) ? v : t;
    t = __builtin_amdgcn_update_dpp(0, v, 0x142, 0xa, 0xf, false); v = ((unsigned)v > (unsigned)t) ? v : t;
    t = __builtin_amdgcn_update_dpp(0, v, 0x143, 0xc, 0xf, false); v = ((unsigned)v > (unsigned)t) ? v : t;
    return (unsigned)__builtin_amdgcn_readlane(v, 63);
}
DEVINL unsigned wave_red_min_u32(unsigned x) {
    int v = (int)x, t;
    t = __builtin_amdgcn_update_dpp(-1, v, 0x111, 0xf, 0xf, false); v = ((unsigned)v < (unsigned)t) ? v : t;
    t = __builtin_amdgcn_update_dpp(-1, v, 0x112, 0xf, 0xf, false); v = ((unsigned)v < (unsigned)t) ? v : t;
    t = __builtin_amdgcn_update_dpp(-1, v, 0x114, 0xf, 0xf, false); v = ((unsigned)v < (unsigned)t) ? v : t;
    t = __builtin_amdgcn_update_dpp(-1, v, 0x118, 0xf, 0xf, false); v = ((unsigned)v < (unsigned)t) ? v : t;
    t = __builtin_amdgcn_update_dpp(-1, v, 0x142, 0xa, 0xf, false); v = ((unsigned)v < (unsigned)t) ? v : t;
    t = __builtin_amdgcn_update_dpp(-1, v, 0x143, 0xc, 0xf, false); v = ((unsigned)v < (unsigned)t) ? v : t;
    return (unsigned)__builtin_amdgcn_readlane(v, 63);
}
// u64 min-reduce (keys monotone, all distinct) -- validated in KNN v3 (R10)
DEVINL unsigned long long wave_red_min_u64(unsigned long long x) {
    unsigned lo = (unsigned)x, hi = (unsigned)(x >> 32);
#define RSTEP(ctl, rm) { \
    unsigned tlo = (unsigned)__builtin_amdgcn_update_dpp(-1, (int)lo, ctl, rm, 0xf, false); \
    unsigned thi = (unsigned)__builtin_amdgcn_update_dpp(-1, (int)hi, ctl, rm, 0xf, false); \
    unsigned long long o = ((unsigned long long)thi << 32) | tlo; \
    unsigned long long c = ((unsigned long long)hi << 32) | lo; \
    if (o < c) { lo = tlo; hi = thi; } }
    RSTEP(0x111, 0xf) RSTEP(0x112, 0xf) RSTEP(0x114, 0xf) RSTEP(0x118, 0xf)
    RSTEP(0x142, 0xa) RSTEP(0x143, 0xc)
#undef RSTEP
    unsigned flo = (unsigned)__builtin_amdgcn_readlane((int)lo, 63);
    unsigned fhi = (unsigned)__builtin_amdgcn_readlane((int)hi, 63);
    return ((unsigned long long)fhi << 32) | flo;
}
// Order-preserving float -> u32 key (handles negative floats; radix-sort trick)
DEVINL unsigned fkey(float f) {
    unsigned b = __float_as_uint(f);
    return b ^ (unsigned)(((int)b >> 31) | (int)0x80000000);
}

// ---------------------------------------------------------------------------
// Fused FPS + KNN + h1 persistent kernel (R13 structure; publish amortized).
// R13 lesson: per-iter RELEASE fetch_add forced a vmcnt(0) drain (~L2 RMW
// latency) inside the serial FPS loop -> producer 390->920us. Fix: cnt[b] has
// a SINGLE writer, so no RMW needed -- cidx stores are relaxed fire-and-forget
// and t0 does ONE release store cnt[b]=g+1 every 8 groups (g%8==7; 511 incl).
// Consumers acquire-load cnt (unchanged); wait at most 8 extra groups.
// ---------------------------------------------------------------------------
__global__ __launch_bounds__(512) void fps_knn_h1_kernel(
    const float* __restrict__ xyz, const float* __restrict__ color,
    const float* __restrict__ w1, const float* __restrict__ b1,
    const float* __restrict__ g1, const float* __restrict__ be1,
    __hip_bfloat16* __restrict__ h1b,
    unsigned* __restrict__ cnt, unsigned* __restrict__ cidx)
{
    alignas(16) __shared__ char shraw[131104];
    const int t = threadIdx.x;

    if (blockIdx.x < 8) {
        // ============== PRODUCER: FPS (R8-exact core) ==============
        const int b = blockIdx.x;
        f32x4* pts = (f32x4*)shraw;
        unsigned long long* sred = (unsigned long long*)(shraw + 131072);
        const float* P = xyz + (size_t)b * Np * 3;
        f32x2 X[8], Y[8], Z[8], MD[8];
#pragma unroll
        for (int i = 0; i < 8; ++i) {
            int p0 = (2 * i) * 512 + t;
            int p1 = p0 + 512;
            float x0 = P[p0 * 3 + 0], y0 = P[p0 * 3 + 1], z0 = P[p0 * 3 + 2];
            float x1 = P[p1 * 3 + 0], y1 = P[p1 * 3 + 1], z1 = P[p1 * 3 + 2];
            X[i] = f32x2{x0, x1}; Y[i] = f32x2{y0, y1}; Z[i] = f32x2{z0, z1};
            pts[p0] = f32x4{x0, y0, z0, 0.f};
            pts[p1] = f32x4{x1, y1, z1, 0.f};
            MD[i] = f32x2{__builtin_inff(), __builtin_inff()};
        }
        if (t < 3) sred[t] = 0ull;
        if (t == 0) {
            __hip_atomic_store(&cidx[b * Gc + 0], 0u, __ATOMIC_RELAXED, __HIP_MEMORY_SCOPE_AGENT);
            __hip_atomic_store(&cnt[b], 1u, __ATOMIC_RELEASE, __HIP_MEMORY_SCOPE_AGENT);
        }
        __syncthreads();
        int last = 0;
        for (int g = 1; g < Gc; ++g) {
            const f32x4 c4 = pts[last];
            const f32x2 cx = {c4.x, c4.x}, cy = {c4.y, c4.y}, cz = {c4.z, c4.z};
            f32x2 bv2 = {0.f, 0.f};
#pragma unroll
            for (int i = 0; i < 8; ++i) {
                f32x2 dx = X[i] - cx;
                f32x2 dy = Y[i] - cy;
                f32x2 dz = Z[i] - cz;
                f32x2 d  = (dx * dx + dy * dy) + dz * dz;   // exact ref form (validated)
                f32x2 m  = MD[i];
                m.x = fminf(m.x, d.x); m.y = fminf(m.y, d.y);
                MD[i] = m;
                bv2.x = fmaxf(bv2.x, m.x); bv2.y = fmaxf(bv2.y, m.y);
            }
            const float bv = fmaxf(bv2.x, bv2.y);
            const unsigned wmax = wave_red_max_u32(__float_as_uint(bv));
            unsigned idx = 0xffffffffu;
#pragma unroll
            for (int i = 7; i >= 0; --i) {
                if (__float_as_uint(MD[i].y) == wmax) idx = (unsigned)((2 * i + 1) * 512 + t);
                if (__float_as_uint(MD[i].x) == wmax) idx = (unsigned)((2 * i) * 512 + t);
            }
            const unsigned widx = wave_red_min_u32(idx);
            if ((t & 63) == 0) {
                unsigned long long pack =
                    ((unsigned long long)wmax << 32) | (unsigned long long)(~widx);
                atomicMax(&sred[g % 3], pack);
            }
            if (t == 1) sred[(g + 1) % 3] = 0ull;
            __syncthreads();
            const unsigned long long w = sred[g % 3];
            const int wi = (int)(~(unsigned)w);
            if (t == 0) {
                __hip_atomic_store(&cidx[b * Gc + g], (unsigned)wi, __ATOMIC_RELAXED, __HIP_MEMORY_SCOPE_AGENT);
                if ((g & 7) == 7)   // batched release publish (once per 8 groups; 511 incl.)
                    __hip_atomic_store(&cnt[b], (unsigned)(g + 1), __ATOMIC_RELEASE, __HIP_MEMORY_SCOPE_AGENT);
            }
            last = wi;
        }
        return;
    }

    // ============== CONSUMER: KNN v3 + h1 ==============
    const int cid  = blockIdx.x - 8;     // 0..247
    const int cb   = cid & 7;            // batch
    const int cj   = cid >> 3;           // 0..30
    const int wave = t >> 6;             // 0..7
    const int sub  = wave & 3;           // wave within 4-wave group
    const int gsel = wave >> 2;          // 0 or 1: which group of the pair
    const int lane = t & 63;
    unsigned long long* wl = (unsigned long long*)shraw;       // [2][128]
    float* fs = (float*)(shraw + 2048);                        // [2][32][6]
    const float* P = xyz + (size_t)cb * Np * 3;
    const float* C = color + (size_t)cb * Np * 3;
    const int pbase = sub * 2048 + lane;

    for (int p = cj; p < 256; p += 31) {
        const int g = 2 * p + gsel;
        if (t == 0) {
            while ((int)__hip_atomic_load(&cnt[cb], __ATOMIC_ACQUIRE, __HIP_MEMORY_SCOPE_AGENT) < 2 * p + 2)
                __builtin_amdgcn_s_sleep(8);
        }
        __syncthreads();
        const unsigned wic = __hip_atomic_load(&cidx[cb * Gc + g], __ATOMIC_RELAXED, __HIP_MEMORY_SCOPE_AGENT);
        const float cx = P[wic * 3 + 0], cy = P[wic * 3 + 1], cz = P[wic * 3 + 2];
        const float cc = __fadd_rn(__fadd_rn(__fmul_rn(cx, cx), __fmul_rn(cy, cy)), __fmul_rn(cz, cz));
        float dr[32];
#pragma unroll
        for (int i = 0; i < 32; ++i) {
            int pp = pbase + i * 64;
            float px = P[pp * 3 + 0], py = P[pp * 3 + 1], pz = P[pp * 3 + 2];
            float dot = __fadd_rn(__fadd_rn(__fmul_rn(cx, px), __fmul_rn(cy, py)), __fmul_rn(cz, pz));
            float q   = __fadd_rn(__fadd_rn(__fmul_rn(px, px), __fmul_rn(py, py)), __fmul_rn(pz, pz));
            dr[i] = __fadd_rn(__fadd_rn(__fmul_rn(-2.0f, dot), cc), q);
        }
        unsigned excl = 0;
        for (int k = 0; k < Kn; ++k) {
            float bd = __builtin_inff();
            int   bs = 0;
#pragma unroll
            for (int i = 0; i < 32; ++i) {
                float d = ((excl >> i) & 1u) ? __builtin_inff() : dr[i];
                if (d < bd) { bd = d; bs = i; }
            }
            unsigned gidx = (unsigned)(pbase + bs * 64);
            unsigned long long win = wave_red_min_u64(
                ((unsigned long long)fkey(bd) << 32) | (unsigned long long)gidx);
            if (lane == 0) wl[gsel * 128 + sub * 32 + k] = win;
            unsigned widx = (unsigned)win;
            if ((widx & 63) == (unsigned)lane) excl |= 1u << ((widx >> 6) & 31);
        }
        __syncthreads();
        // rank merge: threads 0..127 -> group gsel=0, threads 256..383 -> gsel=1
        {
            const int tt = t & 255, half = t >> 8;
            if (tt < 128) {
                const unsigned long long my = wl[half * 128 + tt];
                int rank = 0;
                for (int j = 0; j < 128; ++j) rank += (wl[half * 128 + j] < my) ? 1 : 0;
                if (rank < Kn) {
                    unsigned gi = (unsigned)my;
                    float px = P[gi * 3 + 0], py = P[gi * 3 + 1], pz = P[gi * 3 + 2];
                    float* F = fs + (half * 32 + rank) * 6;
                    F[0] = px - cx; F[1] = py - cy; F[2] = pz - cz;
                    F[3] = C[gi * 3 + 0]; F[4] = C[gi * 3 + 1]; F[5] = C[gi * 3 + 2];
                }
            }
        }
        __syncthreads();
        // h1 for the 64 rows of this pair (validated h1 math, feats from LDS)
#pragma unroll
        for (int rr = 0; rr < 8; ++rr) {
            const int r  = wave * 8 + rr;        // 0..63
            const int gg = r >> 5, k = r & 31;
            const float* F = fs + (gg * 32 + k) * 6;
            float fr[6];
#pragma unroll
            for (int i = 0; i < 6; ++i) fr[i] = F[i];
            const int c0 = lane * 2;
            float a0 = b1[c0], a1 = b1[c0 + 1];
#pragma unroll
            for (int i = 0; i < 6; ++i) {
                a0 = fmaf(w1[c0 * 6 + i], fr[i], a0);
                a1 = fmaf(w1[(c0 + 1) * 6 + i], fr[i], a1);
            }
            float s = a0 + a1;
#pragma unroll
            for (int m = 1; m < 64; m <<= 1) s += __shfl_xor(s, m, 64);
            float mu = s * (1.f / 128.f);
            float d0 = a0 - mu, d1 = a1 - mu;
            float q = d0 * d0 + d1 * d1;
#pragma unroll
            for (int m = 1; m < 64; m <<= 1) q += __shfl_xor(q, m, 64);
            float iv = rsqrtf(q * (1.f / 128.f) + LNEPS);
            float y0 = fmaxf(0.f, d0 * iv * g1[c0] + be1[c0]);
            float y1 = fmaxf(0.f, d1 * iv * g1[c0 + 1] + be1[c0 + 1]);
            __hip_bfloat16* dst = h1b + ((size_t)(cb * Gc + 2 * p + gg) * 32 + k) * 128 + c0;
            dst[0] = __float2bfloat16(y0);
            dst[1] = __float2bfloat16(y1);
        }
        __syncthreads();
    }
}

// ---------------------------------------------------------------------------
// Weight cast f32 -> bf16 (w2, w3, w4)
// ---------------------------------------------------------------------------
__global__ void cast_w_kernel(const float* __restrict__ w2, const float* __restrict__ w3,
                              const float* __restrict__ w4,
                              __hip_bfloat16* __restrict__ o2, __hip_bfloat16* __restrict__ o3,
                              __hip_bfloat16* __restrict__ o4)
{
    int i = blockIdx.x * 256 + threadIdx.x;   // grid covers 262144
    if (i < 256 * 128) o2[i] = __float2bfloat16(w2[i]);
    o3[i] = __float2bfloat16(w3[i]);
    o4[i] = __float2bfloat16(w4[i]);
}

// ---------------------------------------------------------------------------
// GEMM: C[m,n] = sum_k A[m,k] * W[n,k]  (+ epilogues). BM=128, 8 waves.
// EPI 3: +bias, bf16 high-half store + fused per-group col-max into cols 0..255
// EPI 2: +bias, max over 32-row groups, f32 out
// EPI 4: +bias, f32 full-row store to outF (P1 = group-part of h3)
// EPI 6: +P1[grp] (from outF, f32), LayerNorm(BN)*gamma+beta, ReLU, bf16
// ---------------------------------------------------------------------------
template <int BN, int BK, int EPI>
__global__ __launch_bounds__(512, 2) void gemm_kernel(
    const __hip_bfloat16* A, int lda,
    const __hip_bfloat16* __restrict__ Bw, int ldb, int nkt,
    const float* __restrict__ bias,
    const float* __restrict__ gamma, const float* __restrict__ beta,
    __hip_bfloat16* outB, int ocol0,
    float* __restrict__ outF)
{
    constexpr int BM = 128;
    constexpr int WN = BN / 4;
    constexpr int NI = WN / 16;
    constexpr int MI = 4;
    constexpr int RB = BK * 2;           // row bytes in LDS
    constexpr int SWM = BK / 8 - 1;      // swizzle mask (chunks per row - 1)
    constexpr int A_ELE = BM * BK;
    constexpr int B_ELE = BN * BK;
    constexpr int BUF = A_ELE + B_ELE;
    constexpr int ACH = A_ELE * 2 / 16 / 512;
    constexpr int BCH = B_ELE * 2 / 16 / 512;
    __shared__ __hip_bfloat16 smem[2 * BUF];

    const int tid  = threadIdx.x;
    const int wid  = tid >> 6, lane = tid & 63;
    const int wm   = wid >> 2, wn = wid & 3;
    const int lrow = lane & 15, lq = lane >> 4;
    const int m0   = blockIdx.x * BM;

    f32x4 acc[MI][NI] = {};

    auto stage = [&](int buf, int k0) {
        const char* Ab = (const char*)A + ((size_t)m0 * lda + k0) * 2;
        const char* Bb = (const char*)Bw + (size_t)k0 * 2;
        char* sA = (char*)(smem + (size_t)buf * BUF);
        char* sB = sA + A_ELE * 2;
#pragma unroll
        for (int i = 0; i < ACH; ++i) {
            int chunk = i * 512 + tid;
            int Pp = chunk * 16;
            int row = Pp / RB;
            int kb = (Pp % RB) ^ ((row & SWM) << 4);
            const void* g = Ab + (size_t)row * (lda * 2) + kb;
            void* l = sA + (i * 512 + wid * 64) * 16;
            __builtin_amdgcn_global_load_lds((const __attribute__((address_space(1))) void*)g,
                                             (__attribute__((address_space(3))) void*)l, 16, 0, 0);
        }
#pragma unroll
        for (int i = 0; i < BCH; ++i) {
            int chunk = i * 512 + tid;
            int Pp = chunk * 16;
            int n = Pp / RB;
            int kb = (Pp % RB) ^ ((n & SWM) << 4);
            const void* g = Bb + (size_t)n * (ldb * 2) + kb;
            void* l = sB + (i * 512 + wid * 64) * 16;
            __builtin_amdgcn_global_load_lds((const __attribute__((address_space(1))) void*)g,
                                             (__attribute__((address_space(3))) void*)l, 16, 0, 0);
        }
    };

    auto compute = [&](int buf) {
        const char* sA = (const char*)(smem + (size_t)buf * BUF);
        const char* sB = sA + A_ELE * 2;
#pragma unroll
        for (int kk = 0; kk < BK / 32; ++kk) {
            bf16x8 af[MI], bfv[NI];
#pragma unroll
            for (int mi = 0; mi < MI; ++mi) {
                int row = wm * 64 + mi * 16 + lrow;
                int off = row * RB + ((kk * 64 + lq * 16) ^ ((row & SWM) << 4));
                af[mi] = *(const bf16x8*)(sA + off);
            }
#pragma unroll
            for (int ni = 0; ni < NI; ++ni) {
                int n = wn * WN + ni * 16 + lrow;
                int off = n * RB + ((kk * 64 + lq * 16) ^ ((n & SWM) << 4));
                bfv[ni] = *(const bf16x8*)(sB + off);
            }
#pragma unroll
            for (int mi = 0; mi < MI; ++mi)
#pragma unroll
                for (int ni = 0; ni < NI; ++ni)
                    acc[mi][ni] = __builtin_amdgcn_mfma_f32_16x16x32_bf16(af[mi], bfv[ni], acc[mi][ni], 0, 0, 0);
        }
    };

    stage(0, 0);
    __syncthreads();
    int cur = 0;
    for (int kt = 0; kt < nkt; ++kt) {
        if (kt + 1 < nkt) stage(cur ^ 1, (kt + 1) * BK);
        compute(cur);
        __syncthreads();
        cur ^= 1;
    }

    float bv[NI] = {};
    if constexpr (EPI != 6) {
#pragma unroll
        for (int ni = 0; ni < NI; ++ni) bv[ni] = bias[wn * WN + ni * 16 + lrow];
    }

    if constexpr (EPI == 3) {
        // high-half store (h2 result, cols 256..511)
#pragma unroll
        for (int mi = 0; mi < MI; ++mi)
#pragma unroll
            for (int ni = 0; ni < NI; ++ni) {
                int col = ocol0 + wn * WN + ni * 16 + lrow;
#pragma unroll
                for (int j = 0; j < 4; ++j) {
                    int row = wm * 64 + mi * 16 + lq * 4 + j;
                    outB[(size_t)(m0 + row) * 512 + col] = __float2bfloat16(acc[mi][ni][j] + bv[ni]);
                }
            }
        // fused hgmax: per-group (32-row) col-max, broadcast into cols 0..255
        float* hgp = (float*)smem;   // [4][256] f32; safe after loop's last barrier
#pragma unroll
        for (int mi2 = 0; mi2 < 2; ++mi2) {
#pragma unroll
            for (int ni = 0; ni < NI; ++ni) {
                float m = -__builtin_inff();
#pragma unroll
                for (int mh = 0; mh < 2; ++mh) {
                    int mi = mi2 * 2 + mh;
#pragma unroll
                    for (int j = 0; j < 4; ++j) m = fmaxf(m, acc[mi][ni][j] + bv[ni]);
                }
                m = fmaxf(m, __shfl_xor(m, 16, 64));
                m = fmaxf(m, __shfl_xor(m, 32, 64));
                if (lq == 0)
                    hgp[(wm * 2 + mi2) * 256 + wn * WN + ni * 16 + lrow] = m;
            }
        }
        __syncthreads();
#pragma unroll 4
        for (int i = 0; i < 64; ++i) {
            int idx = i * 512 + tid;            // 128 rows x 256 cols
            int row = idx >> 8, col = idx & 255;
            outB[(size_t)(m0 + row) * 512 + col] = __float2bfloat16(hgp[(row >> 5) * 256 + col]);
        }
    } else if constexpr (EPI == 4) {
#pragma unroll
        for (int mi = 0; mi < MI; ++mi)
#pragma unroll
            for (int ni = 0; ni < NI; ++ni) {
                int col = wn * WN + ni * 16 + lrow;
#pragma unroll
                for (int j = 0; j < 4; ++j) {
                    int row = wm * 64 + mi * 16 + lq * 4 + j;
                    outF[(size_t)(m0 + row) * 512 + col] = acc[mi][ni][j] + bv[ni];
                }
            }
    } else if constexpr (EPI == 6) {
        float gv[NI], bev[NI];
#pragma unroll
        for (int ni = 0; ni < NI; ++ni) {
            int col = wn * WN + ni * 16 + lrow;
            gv[ni] = gamma[col]; bev[ni] = beta[col];
        }
        {
            // add group-part P1 (f32, includes b3), uniform across the 32-row group
            const float* P1 = outF;
#pragma unroll
            for (int mi = 0; mi < MI; ++mi) {
                int grow = (m0 >> 5) + wm * 2 + (mi >> 1);
#pragma unroll
                for (int ni = 0; ni < NI; ++ni) {
                    float ad = P1[(size_t)grow * 512 + (wn * WN + ni * 16 + lrow)];
#pragma unroll
                    for (int j = 0; j < 4; ++j) acc[mi][ni][j] += ad;
                }
            }
        }

        float* rs  = (float*)smem;
        float* rq  = rs + BM * 4;
        float* rmu = rq + BM * 4;
        float* riv = rmu + BM;
#pragma unroll
        for (int mi = 0; mi < MI; ++mi) {
#pragma unroll
            for (int j = 0; j < 4; ++j) {
                float s = 0.f, q = 0.f;
#pragma unroll
                for (int ni = 0; ni < NI; ++ni) { float v = acc[mi][ni][j]; s += v; q += v * v; }
#pragma unroll
                for (int m = 1; m < 16; m <<= 1) { s += __shfl_xor(s, m, 64); q += __shfl_xor(q, m, 64); }
                if (lrow == 0) {
                    int row = wm * 64 + mi * 16 + lq * 4 + j;
                    rs[row * 4 + wn] = s;
                    rq[row * 4 + wn] = q;
                }
            }
        }
        __syncthreads();
        if (tid < BM) {
            float S = rs[tid * 4 + 0] + rs[tid * 4 + 1] + rs[tid * 4 + 2] + rs[tid * 4 + 3];
            float Q = rq[tid * 4 + 0] + rq[tid * 4 + 1] + rq[tid * 4 + 2] + rq[tid * 4 + 3];
            float mu = S * (1.f / BN);
            float var = Q * (1.f / BN) - mu * mu;
            rmu[tid] = mu;
            riv[tid] = rsqrtf(var + LNEPS);
        }
        __syncthreads();
#pragma unroll
        for (int mi = 0; mi < MI; ++mi)
#pragma unroll
            for (int j = 0; j < 4; ++j) {
                int row = wm * 64 + mi * 16 + lq * 4 + j;
                float mu = rmu[row], iv = riv[row];
#pragma unroll
                for (int ni = 0; ni < NI; ++ni) {
                    float v = (acc[mi][ni][j] - mu) * iv * gv[ni] + bev[ni];
                    v = fmaxf(v, 0.f);
                    outB[(size_t)(m0 + row) * 512 + (wn * WN + ni * 16 + lrow)] = __float2bfloat16(v);
                }
            }
    } else {
#pragma unroll
        for (int grp = 0; grp < 2; ++grp) {
            float mx[NI];
#pragma unroll
            for (int ni = 0; ni < NI; ++ni) {
                float m = -__builtin_inff();
#pragma unroll
                for (int mh = 0; mh < 2; ++mh) {
                    int mi = grp * 2 + mh;
#pragma unroll
                    for (int j = 0; j < 4; ++j) m = fmaxf(m, acc[mi][ni][j] + bv[ni]);
                }
                mx[ni] = m;
            }
#pragma unroll
            for (int ni = 0; ni < NI; ++ni) {
                mx[ni] = fmaxf(mx[ni], __shfl_xor(mx[ni], 16, 64));
                mx[ni] = fmaxf(mx[ni], __shfl_xor(mx[ni], 32, 64));
            }
            if (lq == 0) {
                int grow = (m0 >> 5) + wm * 2 + grp;
#pragma unroll
                for (int ni = 0; ni < NI; ++ni)
                    outF[(size_t)grow * 512 + wn * WN + ni * 16 + lrow] = mx[ni];
            }
        }
    }
}

// ---------------------------------------------------------------------------
extern "C" void kernel_launch(void* const* d_in, const int* in_sizes, int n_in,
                              void* d_out, int out_size, void* d_ws, size_t ws_size,
                              hipStream_t stream)
{
    const float* xyz   = (const float*)d_in[0];
    const float* color = (const float*)d_in[1];
    const float* w1  = (const float*)d_in[2];
    const float* b1  = (const float*)d_in[3];
    const float* g1  = (const float*)d_in[4];
    const float* be1 = (const float*)d_in[5];
    const float* w2  = (const float*)d_in[6];
    const float* b2  = (const float*)d_in[7];
    const float* w3  = (const float*)d_in[8];
    const float* b3  = (const float*)d_in[9];
    const float* g2  = (const float*)d_in[10];
    const float* be2 = (const float*)d_in[11];
    const float* w4  = (const float*)d_in[12];
    const float* b4  = (const float*)d_in[13];
    float* out = (float*)d_out;

    char* ws = (char*)d_ws;
    size_t off = 0;
    auto alloc = [&](size_t bytes) -> void* {
        void* p = ws + off;
        off += (bytes + 255) & ~(size_t)255;
        return p;
    };
    unsigned* cnt       = (unsigned*)alloc(8 * 4);
    unsigned* cidx      = (unsigned*)alloc((size_t)Bn * Gc * 4);
    __hip_bfloat16* w2b = (__hip_bfloat16*)alloc((size_t)256 * 128 * 2);
    __hip_bfloat16* w3b = (__hip_bfloat16*)alloc((size_t)512 * 512 * 2);
    __hip_bfloat16* w4b = (__hip_bfloat16*)alloc((size_t)512 * 512 * 2);
    __hip_bfloat16* h1b = (__hip_bfloat16*)alloc((size_t)Mrows * 128 * 2);
    __hip_bfloat16* x3  = (__hip_bfloat16*)alloc((size_t)Mrows * 512 * 2);
    // P1 [4096][512] f32 (8.4MB) aliases h1b (33.5MB, dead after the h2 gemm)
    float* P1 = (float*)h1b;
    (void)ws_size; (void)in_sizes; (void)n_in; (void)out_size;

    // zero the producer progress counters (ws is poisoned once, never re-poisoned)
    hipMemsetAsync(cnt, 0, 8 * 4, stream);
    // fused fps(8 producer blocks) + knn/h1(248 consumer blocks); 131.1KB LDS
    // => 1 block/CU => all 256 blocks co-resident => handshake deadlock-free
    fps_knn_h1_kernel<<<256, 512, 0, stream>>>(xyz, color, w1, b1, g1, be1, h1b, cnt, cidx);
    cast_w_kernel<<<1024, 256, 0, stream>>>(w2, w3, w4, w2b, w3b, w4b);
    // h2: A=h1b (K=128), writes h2 into x3 cols 256..511 + hg broadcast into 0..255
    gemm_kernel<256, 32, 3><<<Mrows / 128, 512, 0, stream>>>(h1b, 128, w2b, 128, 4,  b2, nullptr, nullptr, x3, 256, nullptr);
    // P1[g][o] = hg[g] @ w3[:, :256]^T + b3   (one x3 row per group via lda=512*32)
    gemm_kernel<512, 32, 4><<<Bn * Gc / 128, 512, 0, stream>>>(x3, 512 * 32, w3b, 512, 8, b3, nullptr, nullptr, nullptr, 0, P1);
    // h3: K=256 row-part (A = x3 cols 256.., W = w3 cols 256..), + P1[grp], LN, ReLU, in-place
    gemm_kernel<512, 32, 6><<<Mrows / 128, 512, 0, stream>>>(x3 + 256, 512, w3b + 256, 512, 8, nullptr, g2, be2, x3, 0, P1);
    // h4: K=512, group max-pool, f32 out
    gemm_kernel<512, 32, 2><<<Mrows / 128, 512, 0, stream>>>(x3, 512, w4b, 512, 16, b4, nullptr, nullptr, nullptr, 0, out);
}